// Round 4
// baseline (1476.580 us; speedup 1.0000x reference)
//
#include <hip/hip_runtime.h>

typedef unsigned short u16;
typedef unsigned int   u32;

#define T_TOK 4096
#define D_DIM 1024
#define H_DIM 512
#define E_NUM 8
#define RT    32          // rows per fused tile
#define MAXP  4608        // padded entries per pass (4096 + 8*31 max, rounded up)

// ---------- bf16 helpers (LDS act compression only) ----------
__device__ __forceinline__ float bf2f(u16 u) {
    return __uint_as_float(((u32)u) << 16);
}
__device__ __forceinline__ u16 f2bf(float f) {
    u32 x = __float_as_uint(f);
    x += 0x7fffu + ((x >> 16) & 1u);   // round-to-nearest-even
    return (u16)(x >> 16);
}

// ---------- init: zero control ints, fill entry arrays with -1 ----------
__global__ void init_kernel(int* __restrict__ ws_i,
                            int* __restrict__ e0, int* __restrict__ e1)
{
    const int tid = threadIdx.x;
    for (int i = tid; i < 1024; i += 256) ws_i[i] = 0;
    for (int i = tid; i < MAXP; i += 256) { e0[i] = -1; e1[i] = -1; }
}

// ---------- router: logits, top-2 softmax gates, per-(e,k) bucket counts ----------
__global__ __launch_bounds__(256) void router_kernel(
    const float* __restrict__ x, const float* __restrict__ wr,
    float* __restrict__ logits_out, int* __restrict__ counts,
    int* __restrict__ top_e, float* __restrict__ top_g)
{
    const int tid  = threadIdx.x;
    const int lane = tid & 63;
    const int t    = blockIdx.x * 4 + (tid >> 6);   // one wave per token

    float acc[E_NUM] = {0.f,0.f,0.f,0.f,0.f,0.f,0.f,0.f};
    const float* xr = x + (size_t)t * D_DIM;
    #pragma unroll
    for (int i = 0; i < 16; ++i) {
        const int d = i * 64 + lane;
        const float xv = xr[d];
        #pragma unroll
        for (int e = 0; e < E_NUM; ++e)
            acc[e] += xv * wr[e * D_DIM + d];
    }
    #pragma unroll
    for (int off = 32; off >= 1; off >>= 1) {
        #pragma unroll
        for (int e = 0; e < E_NUM; ++e)
            acc[e] += __shfl_xor(acc[e], off);
    }
    if (lane == 0) {
        #pragma unroll
        for (int e = 0; e < E_NUM; ++e)
            logits_out[t * E_NUM + e] = acc[e];
        // top-2 (ties -> lowest index, matching jax.lax.top_k)
        int i0 = 0; float v0 = acc[0];
        #pragma unroll
        for (int e = 1; e < E_NUM; ++e) { if (acc[e] > v0) { v0 = acc[e]; i0 = e; } }
        int i1 = (i0 == 0) ? 1 : 0; float v1 = acc[i1];
        #pragma unroll
        for (int e = 0; e < E_NUM; ++e) { if (e != i0 && e != i1 && acc[e] > v1) { v1 = acc[e]; i1 = e; } }
        const float ed = __expf(v1 - v0);      // <= 1, no overflow
        const float g0 = 1.f / (1.f + ed);
        const float g1 = 1.f - g0;
        top_e[2 * t]     = i0;  top_e[2 * t + 1] = i1;
        top_g[2 * t]     = g0;  top_g[2 * t + 1] = g1;
        atomicAdd(&counts[2 * i0 + 0], 1);   // bucket (e=i0, k=0)
        atomicAdd(&counts[2 * i1 + 1], 1);   // bucket (e=i1, k=1)
    }
}

// ---------- scan: padded offsets (mult of RT), cursors, per-pass tile tables ----------
// ws_i: [0..15] counts, [32..47] cursors, [64..79] offsets,
//       [96..97] ntiles per pass, [128..287] table pass0, [352..511] table pass1
__global__ void scan_kernel(int* __restrict__ ws_i)
{
    if (threadIdx.x != 0 || blockIdx.x != 0) return;
    int* counts  = ws_i;
    int* cursors = ws_i + 32;
    int* offsets = ws_i + 64;
    int* ntiles  = ws_i + 96;
    for (int k = 0; k < 2; ++k) {
        int* tab = ws_i + (k ? 352 : 128);
        int s = 0, nt = 0;
        for (int e = 0; e < E_NUM; ++e) {
            const int b = 2 * e + k;
            offsets[b] = s;
            cursors[b] = s;
            const int c     = counts[b];
            const int tiles = (c + RT - 1) / RT;
            for (int j = 0; j < tiles && nt < 160; ++j)
                tab[nt++] = (b << 20) | (s + j * RT);
            s += tiles * RT;
        }
        ntiles[k] = nt;
    }
}

// ---------- scatter: compact (t,k) pairs into per-(e,k) padded buckets ----------
__global__ __launch_bounds__(256) void scatter_kernel(
    const int* __restrict__ top_e, int* __restrict__ cursors,
    int* __restrict__ e0, int* __restrict__ e1)
{
    const int idx = blockIdx.x * 256 + threadIdx.x;  // idx = 2*t + k
    const int e   = top_e[idx] & 7;                  // clamp (paranoia)
    const int k   = idx & 1;
    const int b   = 2 * e + k;
    int pos = atomicAdd(&cursors[b], 1);
    if (pos >= MAXP) pos = MAXP - 1;                 // clamp (paranoia)
    (k ? e1 : e0)[pos] = idx;
}

// ---------- fused expert kernel: 32 bucket rows -> GEMM1+SwiGLU (LDS) -> GEMM2 -> out ----------
// pass 0: plain store (k=0 buckets cover every token exactly once)
// pass 1: read-modify-write (stream order guarantees pass 0 done)
__global__ __launch_bounds__(256) void fused_kernel(
    const float* __restrict__ x, const float* __restrict__ w_in,
    const float* __restrict__ w_out, const int* __restrict__ ws_i,
    const int* __restrict__ entries, const float* __restrict__ top_g,
    float* __restrict__ out, int pass)
{
    const int nt = ws_i[96 + pass];
    if ((int)blockIdx.x >= nt) return;               // uniform, before any barrier
    const int tile = ws_i[(pass ? 352 : 128) + blockIdx.x];
    const int b    = tile >> 20;
    const int row0 = tile & 0xFFFFF;                 // global padded row in this pass's entries
    const int e    = b >> 1;

    __shared__ u16   act[RT][512];      // SwiGLU output, bf16-compressed
    __shared__ float As[RT][36];        // [k][row], pitch 36 (144B = 9*16, float4-aligned)
    __shared__ float Bs[RT][132];       // [k][col], pitch 132 (528B = 33*16); reused as hS
    __shared__ int   entL[RT];
    __shared__ int   tokL[RT];
    __shared__ float gateL[RT];

    const int tid = threadIdx.x;
    if (tid < RT) {
        const int ent = entries[row0 + tid];
        entL[tid]  = ent;
        tokL[tid]  = (ent < 0) ? -1 : ((ent >> 1) & (T_TOK - 1));
        gateL[tid] = (ent < 0) ? 0.f : top_g[ent & 8191];
    }
    __syncthreads();

    const int tx   = tid & 31;          // col group (4 cols of 128)
    const int ty   = tid >> 5;          // row group (4 rows of 32)
    const int arow = tid >> 3;          // A-loader: row 0..31
    const int aseg = tid & 7;           // A-loader: k-seg (4 floats)

    const int tokA = tokL[arow];
    const float* aptr = x + ((size_t)(tokA < 0 ? 0 : tokA) << 10) + (aseg << 2);
    float* hS = &Bs[0][0];              // alias, pitch 132

    // ================= phase 1: h = x @ w_in[e]^T, SwiGLU -> act =================
    for (int nc = 0; nc < 8; ++nc) {
        float c[4][4] = {};
        for (int k0 = 0; k0 < 1024; k0 += 32) {
            float4 va = make_float4(0.f, 0.f, 0.f, 0.f);
            if (tokA >= 0) va = *(const float4*)(aptr + k0);
            float4 vb[4];
            #pragma unroll
            for (int s = 0; s < 4; ++s) {
                const int seg = (tid << 2) + s;      // 0..1023
                const int br  = seg >> 3;            // 0..127
                const int ks  = (seg & 7) << 2;      // 0,4,..,28
                const int wrow = (br < 64) ? (nc * 64 + br) : (448 + nc * 64 + br);
                vb[s] = *(const float4*)(w_in + ((size_t)e << 20) + ((size_t)wrow << 10) + k0 + ks);
            }
            __syncthreads();                          // prior As/Bs (or hS) reads done
            As[aseg * 4 + 0][arow] = va.x;
            As[aseg * 4 + 1][arow] = va.y;
            As[aseg * 4 + 2][arow] = va.z;
            As[aseg * 4 + 3][arow] = va.w;
            #pragma unroll
            for (int s = 0; s < 4; ++s) {
                const int seg = (tid << 2) + s;
                const int br  = seg >> 3;
                const int ks  = (seg & 7) << 2;
                Bs[ks + 0][br] = vb[s].x; Bs[ks + 1][br] = vb[s].y;
                Bs[ks + 2][br] = vb[s].z; Bs[ks + 3][br] = vb[s].w;
            }
            __syncthreads();
            #pragma unroll
            for (int kk = 0; kk < 32; ++kk) {
                const float4 a  = *(const float4*)(&As[kk][ty << 2]);
                const float4 bq = *(const float4*)(&Bs[kk][tx << 2]);
                c[0][0] += a.x * bq.x; c[0][1] += a.x * bq.y; c[0][2] += a.x * bq.z; c[0][3] += a.x * bq.w;
                c[1][0] += a.y * bq.x; c[1][1] += a.y * bq.y; c[1][2] += a.y * bq.z; c[1][3] += a.y * bq.w;
                c[2][0] += a.z * bq.x; c[2][1] += a.z * bq.y; c[2][2] += a.z * bq.z; c[2][3] += a.z * bq.w;
                c[3][0] += a.w * bq.x; c[3][1] += a.w * bq.y; c[3][2] += a.w * bq.z; c[3][3] += a.w * bq.w;
            }
        }
        __syncthreads();                              // all Bs reads done before hS overwrite
        #pragma unroll
        for (int i = 0; i < 4; ++i)
            #pragma unroll
            for (int j = 0; j < 4; ++j)
                hS[(ty * 4 + i) * 132 + (tx * 4 + j)] = c[i][j];
        __syncthreads();
        {   // SwiGLU: act[row][nc*64 + col] = silu(h_a) * h_b   (bf16-compressed)
            const int row = tid >> 3;
            const int cs  = (tid & 7) << 3;
            #pragma unroll
            for (int j = 0; j < 8; ++j) {
                const float aa = hS[row * 132 + cs + j];
                const float bb = hS[row * 132 + 64 + cs + j];
                const float sv = aa / (1.f + __expf(-aa));
                act[row][nc * 64 + cs + j] = f2bf(sv * bb);
            }
        }
        __syncthreads();                              // hS reads done before next staging
    }
    __syncthreads();                                  // act fully written before phase 2 reads

    // ================= phase 2: out_tile = act @ w_out[e]^T, gated =================
    for (int dc = 0; dc < 8; ++dc) {
        float c[4][4] = {};
        for (int k0 = 0; k0 < 512; k0 += 32) {
            const uint2 va = *(const uint2*)(&act[arow][k0 + (aseg << 2)]);  // 4 bf16
            float4 vb[4];
            #pragma unroll
            for (int s = 0; s < 4; ++s) {
                const int seg = (tid << 2) + s;
                const int br  = seg >> 3;
                const int ks  = (seg & 7) << 2;
                const int wrow = dc * 128 + br;       // output col (d)
                vb[s] = *(const float4*)(w_out + ((size_t)e << 19) + ((size_t)wrow << 9) + k0 + ks);
            }
            __syncthreads();
            As[aseg * 4 + 0][arow] = bf2f((u16)(va.x & 0xffff));
            As[aseg * 4 + 1][arow] = bf2f((u16)(va.x >> 16));
            As[aseg * 4 + 2][arow] = bf2f((u16)(va.y & 0xffff));
            As[aseg * 4 + 3][arow] = bf2f((u16)(va.y >> 16));
            #pragma unroll
            for (int s = 0; s < 4; ++s) {
                const int seg = (tid << 2) + s;
                const int br  = seg >> 3;
                const int ks  = (seg & 7) << 2;
                Bs[ks + 0][br] = vb[s].x; Bs[ks + 1][br] = vb[s].y;
                Bs[ks + 2][br] = vb[s].z; Bs[ks + 3][br] = vb[s].w;
            }
            __syncthreads();
            #pragma unroll
            for (int kk = 0; kk < 32; ++kk) {
                const float4 a  = *(const float4*)(&As[kk][ty << 2]);
                const float4 bq = *(const float4*)(&Bs[kk][tx << 2]);
                c[0][0] += a.x * bq.x; c[0][1] += a.x * bq.y; c[0][2] += a.x * bq.z; c[0][3] += a.x * bq.w;
                c[1][0] += a.y * bq.x; c[1][1] += a.y * bq.y; c[1][2] += a.y * bq.z; c[1][3] += a.y * bq.w;
                c[2][0] += a.z * bq.x; c[2][1] += a.z * bq.y; c[2][2] += a.z * bq.z; c[2][3] += a.z * bq.w;
                c[3][0] += a.w * bq.x; c[3][1] += a.w * bq.y; c[3][2] += a.w * bq.z; c[3][3] += a.w * bq.w;
            }
        }
        #pragma unroll
        for (int i = 0; i < 4; ++i) {
            const int r   = ty * 4 + i;
            const int ent = entL[r];
            if (ent >= 0) {
                const float g = gateL[r];
                const int   t = ent >> 1;
                float* orow = out + ((size_t)t << 10) + dc * 128 + tx * 4;
                float4 o;
                o.x = g * c[i][0]; o.y = g * c[i][1];
                o.z = g * c[i][2]; o.w = g * c[i][3];
                if (pass) {
                    const float4 prev = *(const float4*)orow;
                    o.x += prev.x; o.y += prev.y; o.z += prev.z; o.w += prev.w;
                }
                *(float4*)orow = o;
            }
        }
        // next dc's first __syncthreads orders Bs reuse; stores touch no LDS
    }
}

extern "C" void kernel_launch(void* const* d_in, const int* in_sizes, int n_in,
                              void* d_out, int out_size, void* d_ws, size_t ws_size,
                              hipStream_t stream)
{
    (void)in_sizes; (void)n_in; (void)out_size; (void)ws_size;
    const float* x     = (const float*)d_in[0];   // [4096,1024] fp32
    const float* wr    = (const float*)d_in[1];   // [8,1024]
    const float* w_in  = (const float*)d_in[2];   // [8,1024,1024]
    const float* w_out = (const float*)d_in[3];   // [8,1024,512]
    float* out = (float*)d_out;                   // [4096*1024] out ++ [4096*8] logits

    // workspace layout (~111 KB total):
    char* ws = (char*)d_ws;
    int*   ws_i  = (int*)ws;                          //  4 KB control + tile tables
    int*   e0    = (int*)(ws + 8192);                 // 18 KB padded entries, pass 0
    int*   e1    = (int*)(ws + 26624);                // 18 KB padded entries, pass 1
    int*   top_e = (int*)(ws + 45056);                // 32 KB
    float* top_g = (float*)(ws + 77824);              // 32 KB
    int*   counts  = ws_i;
    int*   cursors = ws_i + 32;

    init_kernel<<<1, 256, 0, stream>>>(ws_i, e0, e1);
    router_kernel<<<1024, 256, 0, stream>>>(x, wr, out + (size_t)T_TOK * D_DIM,
                                            counts, top_e, top_g);
    scan_kernel<<<1, 64, 0, stream>>>(ws_i);
    scatter_kernel<<<32, 256, 0, stream>>>(top_e, cursors, e0, e1);
    fused_kernel<<<160, 256, 0, stream>>>(x, w_in, w_out, ws_i, e0, top_g, out, 0);
    fused_kernel<<<160, 256, 0, stream>>>(x, w_in, w_out, ws_i, e1, top_g, out, 1);
}

// Round 5
// 358.917 us; speedup vs baseline: 4.1140x; 4.1140x over previous
//
#include <hip/hip_runtime.h>

typedef unsigned short u16;
typedef unsigned int   u32;

#define T_TOK 4096
#define D_DIM 1024
#define H_DIM 512
#define E_NUM 8
#define RT    32          // rows per fused (fallback) tile
#define NP1   4608        // padded entries per pass (buckets padded to 64)
#define MAXP  4608

typedef __bf16 bf16x8 __attribute__((ext_vector_type(8)));
typedef float  f32x4  __attribute__((ext_vector_type(4)));

// ---------- bf16 helpers ----------
__device__ __forceinline__ float bf2f(u16 u) {
    return __uint_as_float(((u32)u) << 16);
}
__device__ __forceinline__ u16 f2bf(float f) {
    u32 x = __float_as_uint(f);
    x += 0x7fffu + ((x >> 16) & 1u);   // round-to-nearest-even
    return (u16)(x >> 16);
}

#define LDF(arr, r, koff) __builtin_bit_cast(bf16x8, *(const uint4*)(&arr[r][koff]))
#define MFMA(a, b, c) __builtin_amdgcn_mfma_f32_16x16x32_bf16(a, b, c, 0, 0, 0)

// ---------- init ----------
__global__ void init_kernel(int* __restrict__ ws_i,
                            int* __restrict__ e0, int* __restrict__ e1)
{
    const int tid = threadIdx.x;
    for (int i = tid; i < 1024; i += 256) ws_i[i] = 0;
    for (int i = tid; i < MAXP; i += 256) { e0[i] = -1; e1[i] = -1; }
}

// ---------- router ----------
__global__ __launch_bounds__(256) void router_kernel(
    const float* __restrict__ x, const float* __restrict__ wr,
    float* __restrict__ logits_out, int* __restrict__ counts,
    int* __restrict__ top_e, float* __restrict__ top_g)
{
    const int tid  = threadIdx.x;
    const int lane = tid & 63;
    const int t    = blockIdx.x * 4 + (tid >> 6);

    float acc[E_NUM] = {0.f,0.f,0.f,0.f,0.f,0.f,0.f,0.f};
    const float* xr = x + (size_t)t * D_DIM;
    #pragma unroll
    for (int i = 0; i < 16; ++i) {
        const int d = i * 64 + lane;
        const float xv = xr[d];
        #pragma unroll
        for (int e = 0; e < E_NUM; ++e)
            acc[e] += xv * wr[e * D_DIM + d];
    }
    #pragma unroll
    for (int off = 32; off >= 1; off >>= 1) {
        #pragma unroll
        for (int e = 0; e < E_NUM; ++e)
            acc[e] += __shfl_xor(acc[e], off);
    }
    if (lane == 0) {
        #pragma unroll
        for (int e = 0; e < E_NUM; ++e)
            logits_out[t * E_NUM + e] = acc[e];
        int i0 = 0; float v0 = acc[0];
        #pragma unroll
        for (int e = 1; e < E_NUM; ++e) { if (acc[e] > v0) { v0 = acc[e]; i0 = e; } }
        int i1 = (i0 == 0) ? 1 : 0; float v1 = acc[i1];
        #pragma unroll
        for (int e = 0; e < E_NUM; ++e) { if (e != i0 && e != i1 && acc[e] > v1) { v1 = acc[e]; i1 = e; } }
        const float ed = __expf(v1 - v0);
        const float g0 = 1.f / (1.f + ed);
        const float g1 = 1.f - g0;
        top_e[2 * t]     = i0;  top_e[2 * t + 1] = i1;
        top_g[2 * t]     = g0;  top_g[2 * t + 1] = g1;
        atomicAdd(&counts[2 * i0 + 0], 1);
        atomicAdd(&counts[2 * i1 + 1], 1);
    }
}

// ---------- scan: 64-padded offsets + tables for fused(RT=32) and mfma(RT=64) ----------
// ws_i: [0..15] counts, [32..47] cursors, [64..79] offsets,
// [96..97] fused ntiles, fused tabs @128/@352 (<=143 each)
// [99] g1 ntiles, tab @512 (<=144); [100..101] g2 ntiles, tabs @768/@896 (<=72)
__global__ void scan_kernel(int* __restrict__ ws_i)
{
    if (threadIdx.x != 0 || blockIdx.x != 0) return;
    int* counts  = ws_i;
    int* cursors = ws_i + 32;
    int* offsets = ws_i + 64;
    for (int k = 0; k < 2; ++k) {
        int s = 0, ntf = 0, nt2 = 0;
        int* tabf = ws_i + (k ? 352 : 128);
        int* tab2 = ws_i + (k ? 896 : 768);
        for (int e = 0; e < E_NUM; ++e) {
            const int b = 2 * e + k;
            offsets[b] = s; cursors[b] = s;
            const int pc = (counts[b] + 63) & ~63;
            for (int j = 0; j < pc / 32 && ntf < 144; ++j) tabf[ntf++] = (b << 20) | (s + j * 32);
            for (int j = 0; j < pc / 64 && nt2 < 72;  ++j) tab2[nt2++] = (e << 16) | (s + j * 64);
            s += pc;
        }
        ws_i[96 + k]  = ntf;
        ws_i[100 + k] = nt2;
    }
    int nt1 = 0;
    for (int k = 0; k < 2; ++k) {
        const int n2 = ws_i[100 + k];
        const int* tab2 = ws_i + (k ? 896 : 768);
        for (int j = 0; j < n2 && nt1 < 144; ++j) {
            const int t = tab2[j];
            ws_i[512 + nt1++] = (t & 0xFFFF0000) | ((t & 0xFFFF) + k * NP1);
        }
    }
    ws_i[99] = nt1;
}

// ---------- scatter ----------
__global__ __launch_bounds__(256) void scatter_kernel(
    const int* __restrict__ top_e, int* __restrict__ cursors,
    int* __restrict__ e0, int* __restrict__ e1)
{
    const int idx = blockIdx.x * 256 + threadIdx.x;  // idx = 2*t + k
    const int e   = top_e[idx] & 7;
    const int k   = idx & 1;
    const int b   = 2 * e + k;
    int pos = atomicAdd(&cursors[b], 1);
    if (pos >= MAXP) pos = MAXP - 1;
    (k ? e1 : e0)[pos] = idx;
}

// ================== MFMA path ==================

// g1: act[rb+row][0..511] = silu(x@w_in_a^T) * (x@w_in_b^T)   (bf16)
// grid: (8 nc, 144 row-tiles); block 256 = 4 waves; M=64, N=64a+64b, K=1024
__global__ __launch_bounds__(256) void g1_mfma(
    const float* __restrict__ x, const float* __restrict__ w_in,
    const int* __restrict__ ws_i, const int* __restrict__ e0,
    const int* __restrict__ e1, u16* __restrict__ act)
{
    const int nt = ws_i[99];
    if ((int)blockIdx.y >= nt) return;
    const int tile = ws_i[512 + blockIdx.y];
    const int e  = tile >> 16;
    const int rb = tile & 0xFFFF;        // global padded row base (mult 64)
    const int nc = blockIdx.x;           // act cols nc*64..+63

    __shared__ u16 xs[64][72];           // [row][k] bf16
    __shared__ u16 wt[128][72];          // rows 0..63: w_in[nc*64+r]; 64..127: w_in[512+nc*64+(r-64)]
    __shared__ int tokL[64];

    const int tid = threadIdx.x;
    if (tid < 64) {
        const int ent = (rb >= NP1) ? e1[rb - NP1 + tid] : e0[rb + tid];
        tokL[tid] = (ent < 0) ? 0 : (ent >> 1);   // holes -> row 0 (finite junk, never combined)
    }
    __syncthreads();

    const int wid = tid >> 6;
    const int ln  = tid & 63;
    const int qd  = ln >> 4;
    const int lm  = ln & 15;
    const int srow = tid >> 4;           // 0..15 (staging row group)
    const int sseg = tid & 15;           // float4 seg within 64-k chunk

    int xtok[4];
    #pragma unroll
    for (int s = 0; s < 4; ++s) xtok[s] = tokL[s * 16 + srow];

    f32x4 accA[4], accB[4];
    #pragma unroll
    for (int i = 0; i < 4; ++i) { accA[i] = (f32x4){0.f,0.f,0.f,0.f}; accB[i] = (f32x4){0.f,0.f,0.f,0.f}; }

    for (int k0 = 0; k0 < 1024; k0 += 64) {
        float4 xv[4], wvv[8];
        #pragma unroll
        for (int s = 0; s < 4; ++s)
            xv[s] = *(const float4*)(x + ((size_t)xtok[s] << 10) + k0 + (sseg << 2));
        #pragma unroll
        for (int s = 0; s < 8; ++s) {
            const int row = s * 16 + srow;
            const int wr  = (row < 64) ? (nc * 64 + row) : (448 + nc * 64 + row);
            wvv[s] = *(const float4*)(w_in + ((size_t)e << 20) + ((size_t)wr << 10) + k0 + (sseg << 2));
        }
        __syncthreads();                  // prior frag reads done
        #pragma unroll
        for (int s = 0; s < 4; ++s) {
            uint2 pk;
            pk.x = (u32)f2bf(xv[s].x) | ((u32)f2bf(xv[s].y) << 16);
            pk.y = (u32)f2bf(xv[s].z) | ((u32)f2bf(xv[s].w) << 16);
            *(uint2*)&xs[s * 16 + srow][sseg << 2] = pk;
        }
        #pragma unroll
        for (int s = 0; s < 8; ++s) {
            uint2 pk;
            pk.x = (u32)f2bf(wvv[s].x) | ((u32)f2bf(wvv[s].y) << 16);
            pk.y = (u32)f2bf(wvv[s].z) | ((u32)f2bf(wvv[s].w) << 16);
            *(uint2*)&wt[s * 16 + srow][sseg << 2] = pk;
        }
        __syncthreads();
        #pragma unroll
        for (int ki = 0; ki < 2; ++ki) {
            const int ko = ki * 32 + (qd << 3);
            const bf16x8 bA = LDF(wt, (wid << 4) + lm, ko);
            const bf16x8 bB = LDF(wt, 64 + (wid << 4) + lm, ko);
            #pragma unroll
            for (int i = 0; i < 4; ++i) {
                const bf16x8 aF = LDF(xs, (i << 4) + lm, ko);
                accA[i] = MFMA(aF, bA, accA[i]);
                accB[i] = MFMA(aF, bB, accB[i]);
            }
        }
    }

    // SwiGLU in registers, write act
    #pragma unroll
    for (int i = 0; i < 4; ++i) {
        #pragma unroll
        for (int r = 0; r < 4; ++r) {
            const float a = accA[i][r], b = accB[i][r];
            const float v = b * a / (1.f + __expf(-a));
            const int row = (i << 4) + (qd << 2) + r;
            act[((size_t)(rb + row) << 9) + (nc << 6) + (wid << 4) + lm] = f2bf(v);
        }
    }
}

// g2: out[tok] (+)= gate * (act_tile @ w_out[e]^T)
// grid: (8 dc, 72 row-tiles); M=64, N=128, K=512
__global__ __launch_bounds__(256) void g2_mfma(
    const u16* __restrict__ act, const float* __restrict__ w_out,
    const int* __restrict__ ws_i, const int* __restrict__ entries,
    const float* __restrict__ top_g, float* __restrict__ out, int pass)
{
    const int nt = ws_i[100 + pass];
    if ((int)blockIdx.y >= nt) return;
    const int tile = ws_i[(pass ? 896 : 768) + blockIdx.y];
    const int e   = tile >> 16;
    const int rbl = tile & 0xFFFF;       // local padded base
    const int dc  = blockIdx.x;          // out cols dc*128..+127
    const int ab  = pass * NP1 + rbl;    // act row base

    __shared__ u16   as_[64][72];
    __shared__ u16   wt2[128][72];
    __shared__ int   entL[64];
    __shared__ float gateL[64];

    const int tid = threadIdx.x;
    if (tid < 64) {
        const int ent = entries[rbl + tid];
        entL[tid]  = ent;
        gateL[tid] = (ent < 0) ? 0.f : top_g[ent];
    }
    __syncthreads();

    const int wid = tid >> 6;
    const int ln  = tid & 63;
    const int qd  = ln >> 4;
    const int lm  = ln & 15;
    const int srow = tid >> 4;
    const int sseg = tid & 15;

    f32x4 acc[4][2];
    #pragma unroll
    for (int i = 0; i < 4; ++i)
        #pragma unroll
        for (int j = 0; j < 2; ++j) acc[i][j] = (f32x4){0.f,0.f,0.f,0.f};

    for (int k0 = 0; k0 < 512; k0 += 64) {
        uint4 av[2];
        float4 wvv[8];
        #pragma unroll
        for (int s = 0; s < 2; ++s) {
            const int idx = (s << 8) + tid;
            const int row = idx >> 3;
            const int seg = idx & 7;
            av[s] = *(const uint4*)(act + ((size_t)(ab + row) << 9) + k0 + (seg << 3));
        }
        #pragma unroll
        for (int s = 0; s < 8; ++s) {
            const int row = s * 16 + srow;
            wvv[s] = *(const float4*)(w_out + ((size_t)e << 19) + ((size_t)((dc << 7) + row) << 9) + k0 + (sseg << 2));
        }
        __syncthreads();
        #pragma unroll
        for (int s = 0; s < 2; ++s) {
            const int idx = (s << 8) + tid;
            const int row = idx >> 3;
            const int seg = idx & 7;
            *(uint4*)&as_[row][seg << 3] = av[s];
        }
        #pragma unroll
        for (int s = 0; s < 8; ++s) {
            uint2 pk;
            pk.x = (u32)f2bf(wvv[s].x) | ((u32)f2bf(wvv[s].y) << 16);
            pk.y = (u32)f2bf(wvv[s].z) | ((u32)f2bf(wvv[s].w) << 16);
            *(uint2*)&wt2[s * 16 + srow][sseg << 2] = pk;
        }
        __syncthreads();
        #pragma unroll
        for (int ki = 0; ki < 2; ++ki) {
            const int ko = ki * 32 + (qd << 3);
            const bf16x8 b0 = LDF(wt2, (wid << 5) + lm, ko);
            const bf16x8 b1 = LDF(wt2, (wid << 5) + 16 + lm, ko);
            #pragma unroll
            for (int i = 0; i < 4; ++i) {
                const bf16x8 aF = LDF(as_, (i << 4) + lm, ko);
                acc[i][0] = MFMA(aF, b0, acc[i][0]);
                acc[i][1] = MFMA(aF, b1, acc[i][1]);
            }
        }
    }

    #pragma unroll
    for (int i = 0; i < 4; ++i) {
        #pragma unroll
        for (int j = 0; j < 2; ++j) {
            #pragma unroll
            for (int r = 0; r < 4; ++r) {
                const int row = (i << 4) + (qd << 2) + r;
                const int ent = entL[row];
                if (ent >= 0) {
                    const int t   = ent >> 1;
                    const int col = (dc << 7) + (wid << 5) + (j << 4) + lm;
                    float* po = out + ((size_t)t << 10) + col;
                    float vv = gateL[row] * acc[i][j][r];
                    if (pass) vv += *po;
                    *po = vv;
                }
            }
        }
    }
}

// ================== fallback fused path (R4, known-good) ==================
__global__ __launch_bounds__(256) void fused_kernel(
    const float* __restrict__ x, const float* __restrict__ w_in,
    const float* __restrict__ w_out, const int* __restrict__ ws_i,
    const int* __restrict__ entries, const float* __restrict__ top_g,
    float* __restrict__ out, int pass)
{
    const int nt = ws_i[96 + pass];
    if ((int)blockIdx.x >= nt) return;
    const int tile = ws_i[(pass ? 352 : 128) + blockIdx.x];
    const int b    = tile >> 20;
    const int row0 = tile & 0xFFFFF;
    const int e    = b >> 1;

    __shared__ u16   act[RT][512];
    __shared__ float As[RT][36];
    __shared__ float Bs[RT][132];
    __shared__ int   entL[RT];
    __shared__ int   tokL[RT];
    __shared__ float gateL[RT];

    const int tid = threadIdx.x;
    if (tid < RT) {
        const int ent = entries[row0 + tid];
        entL[tid]  = ent;
        tokL[tid]  = (ent < 0) ? -1 : ((ent >> 1) & (T_TOK - 1));
        gateL[tid] = (ent < 0) ? 0.f : top_g[ent & 8191];
    }
    __syncthreads();

    const int tx   = tid & 31;
    const int ty   = tid >> 5;
    const int arow = tid >> 3;
    const int aseg = tid & 7;

    const int tokA = tokL[arow];
    const float* aptr = x + ((size_t)(tokA < 0 ? 0 : tokA) << 10) + (aseg << 2);
    float* hS = &Bs[0][0];

    for (int nc = 0; nc < 8; ++nc) {
        float c[4][4] = {};
        for (int k0 = 0; k0 < 1024; k0 += 32) {
            float4 va = make_float4(0.f, 0.f, 0.f, 0.f);
            if (tokA >= 0) va = *(const float4*)(aptr + k0);
            float4 vb[4];
            #pragma unroll
            for (int s = 0; s < 4; ++s) {
                const int seg = (tid << 2) + s;
                const int br  = seg >> 3;
                const int ks  = (seg & 7) << 2;
                const int wrow = (br < 64) ? (nc * 64 + br) : (448 + nc * 64 + br);
                vb[s] = *(const float4*)(w_in + ((size_t)e << 20) + ((size_t)wrow << 10) + k0 + ks);
            }
            __syncthreads();
            As[aseg * 4 + 0][arow] = va.x;
            As[aseg * 4 + 1][arow] = va.y;
            As[aseg * 4 + 2][arow] = va.z;
            As[aseg * 4 + 3][arow] = va.w;
            #pragma unroll
            for (int s = 0; s < 4; ++s) {
                const int seg = (tid << 2) + s;
                const int br  = seg >> 3;
                const int ks  = (seg & 7) << 2;
                Bs[ks + 0][br] = vb[s].x; Bs[ks + 1][br] = vb[s].y;
                Bs[ks + 2][br] = vb[s].z; Bs[ks + 3][br] = vb[s].w;
            }
            __syncthreads();
            #pragma unroll
            for (int kk = 0; kk < 32; ++kk) {
                const float4 a  = *(const float4*)(&As[kk][ty << 2]);
                const float4 bq = *(const float4*)(&Bs[kk][tx << 2]);
                c[0][0] += a.x * bq.x; c[0][1] += a.x * bq.y; c[0][2] += a.x * bq.z; c[0][3] += a.x * bq.w;
                c[1][0] += a.y * bq.x; c[1][1] += a.y * bq.y; c[1][2] += a.y * bq.z; c[1][3] += a.y * bq.w;
                c[2][0] += a.z * bq.x; c[2][1] += a.z * bq.y; c[2][2] += a.z * bq.z; c[2][3] += a.z * bq.w;
                c[3][0] += a.w * bq.x; c[3][1] += a.w * bq.y; c[3][2] += a.w * bq.z; c[3][3] += a.w * bq.w;
            }
        }
        __syncthreads();
        #pragma unroll
        for (int i = 0; i < 4; ++i)
            #pragma unroll
            for (int j = 0; j < 4; ++j)
                hS[(ty * 4 + i) * 132 + (tx * 4 + j)] = c[i][j];
        __syncthreads();
        {
            const int row = tid >> 3;
            const int cs  = (tid & 7) << 3;
            #pragma unroll
            for (int j = 0; j < 8; ++j) {
                const float aa = hS[row * 132 + cs + j];
                const float bb = hS[row * 132 + 64 + cs + j];
                const float sv = aa / (1.f + __expf(-aa));
                act[row][nc * 64 + cs + j] = f2bf(sv * bb);
            }
        }
        __syncthreads();
    }
    __syncthreads();

    for (int dc = 0; dc < 8; ++dc) {
        float c[4][4] = {};
        for (int k0 = 0; k0 < 512; k0 += 32) {
            const uint2 va = *(const uint2*)(&act[arow][k0 + (aseg << 2)]);
            float4 vb[4];
            #pragma unroll
            for (int s = 0; s < 4; ++s) {
                const int seg = (tid << 2) + s;
                const int br  = seg >> 3;
                const int ks  = (seg & 7) << 2;
                const int wrow = dc * 128 + br;
                vb[s] = *(const float4*)(w_out + ((size_t)e << 19) + ((size_t)wrow << 9) + k0 + ks);
            }
            __syncthreads();
            As[aseg * 4 + 0][arow] = bf2f((u16)(va.x & 0xffff));
            As[aseg * 4 + 1][arow] = bf2f((u16)(va.x >> 16));
            As[aseg * 4 + 2][arow] = bf2f((u16)(va.y & 0xffff));
            As[aseg * 4 + 3][arow] = bf2f((u16)(va.y >> 16));
            #pragma unroll
            for (int s = 0; s < 4; ++s) {
                const int seg = (tid << 2) + s;
                const int br  = seg >> 3;
                const int ks  = (seg & 7) << 2;
                Bs[ks + 0][br] = vb[s].x; Bs[ks + 1][br] = vb[s].y;
                Bs[ks + 2][br] = vb[s].z; Bs[ks + 3][br] = vb[s].w;
            }
            __syncthreads();
            #pragma unroll
            for (int kk = 0; kk < 32; ++kk) {
                const float4 a  = *(const float4*)(&As[kk][ty << 2]);
                const float4 bq = *(const float4*)(&Bs[kk][tx << 2]);
                c[0][0] += a.x * bq.x; c[0][1] += a.x * bq.y; c[0][2] += a.x * bq.z; c[0][3] += a.x * bq.w;
                c[1][0] += a.y * bq.x; c[1][1] += a.y * bq.y; c[1][2] += a.y * bq.z; c[1][3] += a.y * bq.w;
                c[2][0] += a.z * bq.x; c[2][1] += a.z * bq.y; c[2][2] += a.z * bq.z; c[2][3] += a.z * bq.w;
                c[3][0] += a.w * bq.x; c[3][1] += a.w * bq.y; c[3][2] += a.w * bq.z; c[3][3] += a.w * bq.w;
            }
        }
        #pragma unroll
        for (int i = 0; i < 4; ++i) {
            const int r   = ty * 4 + i;
            const int ent = entL[r];
            if (ent >= 0) {
                const float g = gateL[r];
                const int   t = ent >> 1;
                float* orow = out + ((size_t)t << 10) + dc * 128 + tx * 4;
                float4 o;
                o.x = g * c[i][0]; o.y = g * c[i][1];
                o.z = g * c[i][2]; o.w = g * c[i][3];
                if (pass) {
                    const float4 prev = *(const float4*)orow;
                    o.x += prev.x; o.y += prev.y; o.z += prev.z; o.w += prev.w;
                }
                *(float4*)orow = o;
            }
        }
    }
}

extern "C" void kernel_launch(void* const* d_in, const int* in_sizes, int n_in,
                              void* d_out, int out_size, void* d_ws, size_t ws_size,
                              hipStream_t stream)
{
    (void)in_sizes; (void)n_in; (void)out_size;
    const float* x     = (const float*)d_in[0];   // [4096,1024] fp32
    const float* wr    = (const float*)d_in[1];   // [8,1024]
    const float* w_in  = (const float*)d_in[2];   // [8,1024,1024]
    const float* w_out = (const float*)d_in[3];   // [8,1024,512]
    float* out = (float*)d_out;                   // [4096*1024] out ++ [4096*8] logits

    char* ws = (char*)d_ws;
    int*   ws_i  = (int*)ws;                          //  4 KB control + tables
    int*   e0    = (int*)(ws + 8192);                 // 18 KB entries pass 0
    int*   e1    = (int*)(ws + 26624);                // 18 KB entries pass 1
    int*   top_e = (int*)(ws + 45056);                // 32 KB
    float* top_g = (float*)(ws + 77824);              // 32 KB
    u16*   act   = (u16*)(ws + 131072);               // 9216*512*2 = 9.4 MB (mfma path only)
    int*   counts  = ws_i;
    int*   cursors = ws_i + 32;

    init_kernel<<<1, 256, 0, stream>>>(ws_i, e0, e1);
    router_kernel<<<1024, 256, 0, stream>>>(x, wr, out + (size_t)T_TOK * D_DIM,
                                            counts, top_e, top_g);
    scan_kernel<<<1, 64, 0, stream>>>(ws_i);
    scatter_kernel<<<32, 256, 0, stream>>>(top_e, cursors, e0, e1);

    if (ws_size >= (size_t)131072 + (size_t)NP1 * 2 * 512 * sizeof(u16)) {
        // MFMA path
        g1_mfma<<<dim3(8, 144), 256, 0, stream>>>(x, w_in, ws_i, e0, e1, act);
        g2_mfma<<<dim3(8, 72), 256, 0, stream>>>(act, w_out, ws_i, e0, top_g, out, 0);
        g2_mfma<<<dim3(8, 72), 256, 0, stream>>>(act, w_out, ws_i, e1, top_g, out, 1);
    } else {
        // fallback: fused fp32 path
        fused_kernel<<<160, 256, 0, stream>>>(x, w_in, w_out, ws_i, e0, top_g, out, 0);
        fused_kernel<<<160, 256, 0, stream>>>(x, w_in, w_out, ws_i, e1, top_g, out, 1);
    }
}

// Round 6
// 257.799 us; speedup vs baseline: 5.7277x; 1.3922x over previous
//
#include <hip/hip_runtime.h>

typedef unsigned short u16;
typedef unsigned int   u32;

#define T_TOK 4096
#define D_DIM 1024
#define H_DIM 512
#define E_NUM 8
#define NP1   4608        // padded entries per pass (buckets padded to 64)
#define MAXP  4608

typedef __bf16 bf16x8 __attribute__((ext_vector_type(8)));
typedef float  f32x4  __attribute__((ext_vector_type(4)));

// ---------- bf16 helpers ----------
__device__ __forceinline__ u16 f2bf(float f) {
    u32 x = __float_as_uint(f);
    x += 0x7fffu + ((x >> 16) & 1u);   // round-to-nearest-even
    return (u16)(x >> 16);
}

#define LDF(arr, r, koff) __builtin_bit_cast(bf16x8, *(const uint4*)(&arr[r][koff]))
#define MFMA(a, b, c) __builtin_amdgcn_mfma_f32_16x16x32_bf16(a, b, c, 0, 0, 0)

// ---------- router: logits + top-2 gates; NO atomics, LDS-staged wr ----------
// block = 256 thr (4 waves), 16 tokens/block, grid 256
__global__ __launch_bounds__(256) void router_kernel(
    const float* __restrict__ x, const float* __restrict__ wr,
    float* __restrict__ logits_out, int* __restrict__ top_e, float* __restrict__ top_g)
{
    __shared__ float wrL[E_NUM][1024];
    const int tid = threadIdx.x;
    #pragma unroll
    for (int i = 0; i < 8; ++i) {
        const int idx = (i * 256 + tid) * 4;          // 0..8188 step 4
        *(float4*)&wrL[0][idx] = *(const float4*)(wr + idx);
    }
    __syncthreads();

    const int lane = tid & 63;
    const int wv   = tid >> 6;
    const int t0   = blockIdx.x * 16 + wv * 4;

    for (int tt = 0; tt < 4; ++tt) {
        const int t = t0 + tt;
        const float* xr = x + ((size_t)t << 10);
        float4 xv[4];
        #pragma unroll
        for (int j = 0; j < 4; ++j)
            xv[j] = *(const float4*)(xr + j * 256 + lane * 4);

        float acc[E_NUM];
        #pragma unroll
        for (int e = 0; e < E_NUM; ++e) acc[e] = 0.f;
        #pragma unroll
        for (int j = 0; j < 4; ++j) {
            #pragma unroll
            for (int e = 0; e < E_NUM; ++e) {
                const float4 w4 = *(const float4*)&wrL[e][j * 256 + lane * 4];
                acc[e] += xv[j].x * w4.x + xv[j].y * w4.y + xv[j].z * w4.z + xv[j].w * w4.w;
            }
        }
        #pragma unroll
        for (int off = 32; off >= 1; off >>= 1) {
            #pragma unroll
            for (int e = 0; e < E_NUM; ++e)
                acc[e] += __shfl_xor(acc[e], off);
        }
        if (lane == 0) {
            #pragma unroll
            for (int e = 0; e < E_NUM; ++e)
                logits_out[t * E_NUM + e] = acc[e];
            int i0 = 0; float v0 = acc[0];
            #pragma unroll
            for (int e = 1; e < E_NUM; ++e) { if (acc[e] > v0) { v0 = acc[e]; i0 = e; } }
            int i1 = (i0 == 0) ? 1 : 0; float v1 = acc[i1];
            #pragma unroll
            for (int e = 0; e < E_NUM; ++e) { if (e != i0 && e != i1 && acc[e] > v1) { v1 = acc[e]; i1 = e; } }
            const float ed = __expf(v1 - v0);
            const float g0 = 1.f / (1.f + ed);
            top_e[2 * t]     = i0;  top_e[2 * t + 1] = i1;
            top_g[2 * t]     = g0;  top_g[2 * t + 1] = 1.f - g0;
        }
    }
}

// ---------- countscan: entry prefill + LDS histogram + offsets/cursors/tables ----------
// ws_i: [0..15] counts, [64..79] offsets, [99] g1 ntiles, [100..101] g2 ntiles,
//       cursors PADDED at [128 + 16*b], g1 tab @512(<=144), g2 tabs @768/@896(<=72)
__global__ __launch_bounds__(256) void countscan_kernel(
    const int* __restrict__ top_e, int* __restrict__ ws_i,
    int* __restrict__ e0, int* __restrict__ e1)
{
    __shared__ int hist[16];
    const int tid = threadIdx.x;
    if (tid < 16) hist[tid] = 0;
    for (int i = tid; i < MAXP; i += 256) { e0[i] = -1; e1[i] = -1; }
    __syncthreads();
    for (int i = tid; i < 2 * T_TOK; i += 256) {
        const int e = top_e[i] & 7;
        atomicAdd(&hist[2 * e + (i & 1)], 1);
    }
    __syncthreads();
    if (tid == 0) {
        for (int k = 0; k < 2; ++k) {
            int s = 0, nt2 = 0;
            int* tab2 = ws_i + (k ? 896 : 768);
            for (int e = 0; e < E_NUM; ++e) {
                const int b = 2 * e + k;
                const int c = hist[b];
                ws_i[b]            = c;
                ws_i[64 + b]       = s;
                ws_i[128 + 16 * b] = s;       // padded cursor (own cache line)
                const int pc = (c + 63) & ~63;
                for (int j = 0; j < pc / 64 && nt2 < 72; ++j)
                    tab2[nt2++] = (e << 16) | (s + j * 64);
                s += pc;
            }
            ws_i[100 + k] = nt2;
        }
        int nt1 = 0;
        for (int k = 0; k < 2; ++k) {
            const int n2 = ws_i[100 + k];
            const int* tab2 = ws_i + (k ? 896 : 768);
            for (int j = 0; j < n2 && nt1 < 144; ++j) {
                const int tl = tab2[j];
                ws_i[512 + nt1++] = (tl & 0xFFFF0000) | ((tl & 0xFFFF) + k * NP1);
            }
        }
        ws_i[99] = nt1;
    }
}

// ---------- scatter: padded cursors (16x less line contention) ----------
__global__ __launch_bounds__(256) void scatter_kernel(
    const int* __restrict__ top_e, int* __restrict__ ws_i,
    int* __restrict__ e0, int* __restrict__ e1)
{
    const int idx = blockIdx.x * 256 + threadIdx.x;  // idx = 2*t + k
    const int e   = top_e[idx] & 7;
    const int k   = idx & 1;
    const int b   = 2 * e + k;
    int pos = atomicAdd(&ws_i[128 + 16 * b], 1);
    if (pos >= MAXP) pos = MAXP - 1;
    (k ? e1 : e0)[pos] = idx;
}

// ================== MFMA path (unchanged from R5) ==================

// g1: act[rb+row][0..511] = silu(x@w_in_a^T) * (x@w_in_b^T)   (bf16)
__global__ __launch_bounds__(256) void g1_mfma(
    const float* __restrict__ x, const float* __restrict__ w_in,
    const int* __restrict__ ws_i, const int* __restrict__ e0,
    const int* __restrict__ e1, u16* __restrict__ act)
{
    const int nt = ws_i[99];
    if ((int)blockIdx.y >= nt) return;
    const int tile = ws_i[512 + blockIdx.y];
    const int e  = tile >> 16;
    const int rb = tile & 0xFFFF;
    const int nc = blockIdx.x;

    __shared__ u16 xs[64][72];
    __shared__ u16 wt[128][72];
    __shared__ int tokL[64];

    const int tid = threadIdx.x;
    if (tid < 64) {
        const int ent = (rb >= NP1) ? e1[rb - NP1 + tid] : e0[rb + tid];
        tokL[tid] = (ent < 0) ? 0 : (ent >> 1);
    }
    __syncthreads();

    const int wid = tid >> 6;
    const int ln  = tid & 63;
    const int qd  = ln >> 4;
    const int lm  = ln & 15;
    const int srow = tid >> 4;
    const int sseg = tid & 15;

    int xtok[4];
    #pragma unroll
    for (int s = 0; s < 4; ++s) xtok[s] = tokL[s * 16 + srow];

    f32x4 accA[4], accB[4];
    #pragma unroll
    for (int i = 0; i < 4; ++i) { accA[i] = (f32x4){0.f,0.f,0.f,0.f}; accB[i] = (f32x4){0.f,0.f,0.f,0.f}; }

    for (int k0 = 0; k0 < 1024; k0 += 64) {
        float4 xv[4], wvv[8];
        #pragma unroll
        for (int s = 0; s < 4; ++s)
            xv[s] = *(const float4*)(x + ((size_t)xtok[s] << 10) + k0 + (sseg << 2));
        #pragma unroll
        for (int s = 0; s < 8; ++s) {
            const int row = s * 16 + srow;
            const int wr  = (row < 64) ? (nc * 64 + row) : (448 + nc * 64 + row);
            wvv[s] = *(const float4*)(w_in + ((size_t)e << 20) + ((size_t)wr << 10) + k0 + (sseg << 2));
        }
        __syncthreads();
        #pragma unroll
        for (int s = 0; s < 4; ++s) {
            uint2 pk;
            pk.x = (u32)f2bf(xv[s].x) | ((u32)f2bf(xv[s].y) << 16);
            pk.y = (u32)f2bf(xv[s].z) | ((u32)f2bf(xv[s].w) << 16);
            *(uint2*)&xs[s * 16 + srow][sseg << 2] = pk;
        }
        #pragma unroll
        for (int s = 0; s < 8; ++s) {
            uint2 pk;
            pk.x = (u32)f2bf(wvv[s].x) | ((u32)f2bf(wvv[s].y) << 16);
            pk.y = (u32)f2bf(wvv[s].z) | ((u32)f2bf(wvv[s].w) << 16);
            *(uint2*)&wt[s * 16 + srow][sseg << 2] = pk;
        }
        __syncthreads();
        #pragma unroll
        for (int ki = 0; ki < 2; ++ki) {
            const int ko = ki * 32 + (qd << 3);
            const bf16x8 bA = LDF(wt, (wid << 4) + lm, ko);
            const bf16x8 bB = LDF(wt, 64 + (wid << 4) + lm, ko);
            #pragma unroll
            for (int i = 0; i < 4; ++i) {
                const bf16x8 aF = LDF(xs, (i << 4) + lm, ko);
                accA[i] = MFMA(aF, bA, accA[i]);
                accB[i] = MFMA(aF, bB, accB[i]);
            }
        }
    }

    #pragma unroll
    for (int i = 0; i < 4; ++i) {
        #pragma unroll
        for (int r = 0; r < 4; ++r) {
            const float a = accA[i][r], b = accB[i][r];
            const float v = b * a / (1.f + __expf(-a));
            const int row = (i << 4) + (qd << 2) + r;
            act[((size_t)(rb + row) << 9) + (nc << 6) + (wid << 4) + lm] = f2bf(v);
        }
    }
}

// g2: out[tok] (+)= gate * (act_tile @ w_out[e]^T)
__global__ __launch_bounds__(256) void g2_mfma(
    const u16* __restrict__ act, const float* __restrict__ w_out,
    const int* __restrict__ ws_i, const int* __restrict__ entries,
    const float* __restrict__ top_g, float* __restrict__ out, int pass)
{
    const int nt = ws_i[100 + pass];
    if ((int)blockIdx.y >= nt) return;
    const int tile = ws_i[(pass ? 896 : 768) + blockIdx.y];
    const int e   = tile >> 16;
    const int rbl = tile & 0xFFFF;
    const int dc  = blockIdx.x;
    const int ab  = pass * NP1 + rbl;

    __shared__ u16   as_[64][72];
    __shared__ u16   wt2[128][72];
    __shared__ int   entL[64];
    __shared__ float gateL[64];

    const int tid = threadIdx.x;
    if (tid < 64) {
        const int ent = entries[rbl + tid];
        entL[tid]  = ent;
        gateL[tid] = (ent < 0) ? 0.f : top_g[ent];
    }
    __syncthreads();

    const int wid = tid >> 6;
    const int ln  = tid & 63;
    const int qd  = ln >> 4;
    const int lm  = ln & 15;
    const int srow = tid >> 4;
    const int sseg = tid & 15;

    f32x4 acc[4][2];
    #pragma unroll
    for (int i = 0; i < 4; ++i)
        #pragma unroll
        for (int j = 0; j < 2; ++j) acc[i][j] = (f32x4){0.f,0.f,0.f,0.f};

    for (int k0 = 0; k0 < 512; k0 += 64) {
        uint4 av[2];
        float4 wvv[8];
        #pragma unroll
        for (int s = 0; s < 2; ++s) {
            const int idx = (s << 8) + tid;
            const int row = idx >> 3;
            const int seg = idx & 7;
            av[s] = *(const uint4*)(act + ((size_t)(ab + row) << 9) + k0 + (seg << 3));
        }
        #pragma unroll
        for (int s = 0; s < 8; ++s) {
            const int row = s * 16 + srow;
            wvv[s] = *(const float4*)(w_out + ((size_t)e << 19) + ((size_t)((dc << 7) + row) << 9) + k0 + (sseg << 2));
        }
        __syncthreads();
        #pragma unroll
        for (int s = 0; s < 2; ++s) {
            const int idx = (s << 8) + tid;
            const int row = idx >> 3;
            const int seg = idx & 7;
            *(uint4*)&as_[row][seg << 3] = av[s];
        }
        #pragma unroll
        for (int s = 0; s < 8; ++s) {
            uint2 pk;
            pk.x = (u32)f2bf(wvv[s].x) | ((u32)f2bf(wvv[s].y) << 16);
            pk.y = (u32)f2bf(wvv[s].z) | ((u32)f2bf(wvv[s].w) << 16);
            *(uint2*)&wt2[s * 16 + srow][sseg << 2] = pk;
        }
        __syncthreads();
        #pragma unroll
        for (int ki = 0; ki < 2; ++ki) {
            const int ko = ki * 32 + (qd << 3);
            const bf16x8 b0 = LDF(wt2, (wid << 5) + lm, ko);
            const bf16x8 b1 = LDF(wt2, (wid << 5) + 16 + lm, ko);
            #pragma unroll
            for (int i = 0; i < 4; ++i) {
                const bf16x8 aF = LDF(as_, (i << 4) + lm, ko);
                acc[i][0] = MFMA(aF, b0, acc[i][0]);
                acc[i][1] = MFMA(aF, b1, acc[i][1]);
            }
        }
    }

    #pragma unroll
    for (int i = 0; i < 4; ++i) {
        #pragma unroll
        for (int j = 0; j < 2; ++j) {
            #pragma unroll
            for (int r = 0; r < 4; ++r) {
                const int row = (i << 4) + (qd << 2) + r;
                const int ent = entL[row];
                if (ent >= 0) {
                    const int t   = ent >> 1;
                    const int col = (dc << 7) + (wid << 5) + (j << 4) + lm;
                    float* po = out + ((size_t)t << 10) + col;
                    float vv = gateL[row] * acc[i][j][r];
                    if (pass) vv += *po;
                    *po = vv;
                }
            }
        }
    }
}

extern "C" void kernel_launch(void* const* d_in, const int* in_sizes, int n_in,
                              void* d_out, int out_size, void* d_ws, size_t ws_size,
                              hipStream_t stream)
{
    (void)in_sizes; (void)n_in; (void)out_size; (void)ws_size;
    const float* x     = (const float*)d_in[0];   // [4096,1024] fp32
    const float* wr    = (const float*)d_in[1];   // [8,1024]
    const float* w_in  = (const float*)d_in[2];   // [8,1024,1024]
    const float* w_out = (const float*)d_in[3];   // [8,1024,512]
    float* out = (float*)d_out;                   // [4096*1024] out ++ [4096*8] logits

    char* ws = (char*)d_ws;
    int*   ws_i  = (int*)ws;                          //  4 KB control + tables
    int*   e0    = (int*)(ws + 8192);                 // 18 KB entries pass 0
    int*   e1    = (int*)(ws + 26624);                // 18 KB entries pass 1
    int*   top_e = (int*)(ws + 45056);                // 32 KB
    float* top_g = (float*)(ws + 77824);              // 32 KB
    u16*   act   = (u16*)(ws + 131072);               // 9216*512*2 = 9.4 MB

    router_kernel<<<256, 256, 0, stream>>>(x, wr, out + (size_t)T_TOK * D_DIM, top_e, top_g);
    countscan_kernel<<<1, 256, 0, stream>>>(top_e, ws_i, e0, e1);
    scatter_kernel<<<32, 256, 0, stream>>>(top_e, ws_i, e0, e1);
    g1_mfma<<<dim3(8, 144), 256, 0, stream>>>(x, w_in, ws_i, e0, e1, act);
    g2_mfma<<<dim3(8, 72), 256, 0, stream>>>(act, w_out, ws_i, e0, top_g, out, 0);
    g2_mfma<<<dim3(8, 72), 256, 0, stream>>>(act, w_out, ws_i, e1, top_g, out, 1);
}